// Round 13
// baseline (129.146 us; speedup 1.0000x reference)
//
#include <hip/hip_runtime.h>
#include <hip/hip_bf16.h>
#include <stdint.h>

// ---------- types ----------
typedef __bf16 bf16x8 __attribute__((ext_vector_type(8)));
typedef __bf16 bf16x4 __attribute__((ext_vector_type(4)));
typedef float  f32x4  __attribute__((ext_vector_type(4)));
typedef float  f32x16 __attribute__((ext_vector_type(16)));

__device__ __forceinline__ unsigned short f2bf(float f) {
    unsigned u = __builtin_bit_cast(unsigned, f);
    u += 0x7fffu + ((u >> 16) & 1u);   // RNE
    return (unsigned short)(u >> 16);
}

__device__ __forceinline__ void gload16(const void* g, void* l) {
    __builtin_amdgcn_global_load_lds((const __attribute__((address_space(1))) void*)g,
                                     (__attribute__((address_space(3))) void*)l, 16, 0, 0);
}

// ---------- fused fp32 -> bf16 convert for x, w_qkv, w_proj (one launch) ----------
#define XN  4194304   // 4096*1024
#define WQN 3145728   // 3072*1024
#define WPN 1048576   // 1024*1024
__global__ void cvt_all(const float* __restrict__ x, const float* __restrict__ wq,
                        const float* __restrict__ wp,
                        unsigned short* __restrict__ xb, unsigned short* __restrict__ wqb,
                        unsigned short* __restrict__ wpb) {
    int i = (blockIdx.x * blockDim.x + threadIdx.x) * 4;
    const float* src; unsigned short* dst; int off;
    if (i < XN)            { src = x;  dst = xb;  off = i; }
    else if (i < XN + WQN) { src = wq; dst = wqb; off = i - XN; }
    else                   { src = wp; dst = wpb; off = i - XN - WQN; }
    float4 v = *(const float4*)(src + off);
    ushort4 o;
    o.x = f2bf(v.x); o.y = f2bf(v.y); o.z = f2bf(v.z); o.w = f2bf(v.w);
    *(ushort4*)(dst + off) = o;
}

// ---------- GEMM C = A * B^T (proven 128x128 structure, R7) ----------
#define BM 128
#define BN 128
#define BKK 64

template<int MODE>
__global__ void gemm_bt(const unsigned short* __restrict__ A,
                        const unsigned short* __restrict__ Bm,
                        int M, int N, int K,
                        float* __restrict__ Cf,
                        unsigned short* __restrict__ Qo,
                        unsigned short* __restrict__ Ko,
                        unsigned short* __restrict__ Vo) {
    __shared__ __align__(16) unsigned short Als[BM * BKK];
    __shared__ __align__(16) unsigned short Bls[BN * BKK];

    const int tid  = threadIdx.x;
    const int lane = tid & 63;
    const int wave = tid >> 6;
    const int wm = wave >> 1, wn = wave & 1;
    const int nwg = gridDim.x * gridDim.y;
    const int lid = blockIdx.y * gridDim.x + blockIdx.x;
    const int cpx = nwg >> 3;
    const int swz = (lid & 7) * cpx + (lid >> 3);
    const int m0 = (swz / gridDim.x) * BM, n0 = (swz % gridDim.x) * BN;
    const int l16 = lane & 15, lg = lane >> 4;

    f32x4 acc[4][4];
#pragma unroll
    for (int i = 0; i < 4; i++)
#pragma unroll
        for (int j = 0; j < 4; j++) acc[i][j] = f32x4{0.f, 0.f, 0.f, 0.f};

    const int r0 = tid >> 3;
    const int c8 = tid & 7;

    for (int k0 = 0; k0 < K; k0 += BKK) {
        __syncthreads();
#pragma unroll
        for (int i = 0; i < 4; i++) {
            gload16(A  + (size_t)(m0 + r0 + i * 32) * K + k0 + c8 * 8,
                    Als + i * 2048 + wave * 512);
            gload16(Bm + (size_t)(n0 + r0 + i * 32) * K + k0 + c8 * 8,
                    Bls + i * 2048 + wave * 512);
        }
        __syncthreads();
#pragma unroll
        for (int ks = 0; ks < 2; ++ks) {
            const int koff = ks * 32 + lg * 8;
            bf16x8 af[4], bfv[4];
#pragma unroll
            for (int mf = 0; mf < 4; ++mf)
                af[mf] = *(const bf16x8*)(Als + (wm * 64 + mf * 16 + l16) * BKK + koff);
#pragma unroll
            for (int nf = 0; nf < 4; ++nf)
                bfv[nf] = *(const bf16x8*)(Bls + (wn * 64 + nf * 16 + l16) * BKK + koff);
#pragma unroll
            for (int mf = 0; mf < 4; ++mf)
#pragma unroll
                for (int nf = 0; nf < 4; ++nf)
                    acc[mf][nf] = __builtin_amdgcn_mfma_f32_16x16x32_bf16(af[mf], bfv[nf], acc[mf][nf], 0, 0, 0);
        }
    }

#pragma unroll
    for (int mf = 0; mf < 4; ++mf) {
        int gm = m0 + wm * 64 + mf * 16 + (lg << 2);
#pragma unroll
        for (int nf = 0; nf < 4; ++nf) {
            int gn = n0 + wn * 64 + nf * 16 + l16;
            if (MODE == 0) {
                int which = gn >> 10;
                int rem = gn & 1023;
                int h = rem >> 6, d = rem & 63;
                unsigned short* dst = (which == 0) ? Qo : (which == 1) ? Ko : Vo;
                float s = (which == 0) ? 0.180336884f : 1.0f;   // 0.125 * log2(e) for Q
#pragma unroll
                for (int j = 0; j < 4; j++) {
                    int m = gm + j;
                    int b = m >> 11, t = m & 2047;
                    dst[((size_t)((b << 4) + h) * 2048 + t) * 64 + d] = f2bf(acc[mf][nf][j] * s);
                }
            } else {
#pragma unroll
                for (int j = 0; j < 4; j++)
                    Cf[(size_t)(gm + j) * N + gn] = acc[mf][nf][j];
            }
        }
    }
}

// ---------- causal flash attention: 32x32 MFMA, sequential 32-key halves ----------
// LDS-read-bound fix (R7 counters: 288 b128/CU/tile x 12cyc = the wall).
// 256 thr = 4 waves x 32 q-rows (QBLK=128); LPT 1D grid (512 blocks).
// Per 32-key half: 4 K-reads + 2 P + 4 V = 10 b128 per 32q — 1.8x less than R7.
// Only ONE f32x16 score live (sequential halves) -> ~110 VGPR, fits without spill.
// K staged via double-buffered global_load_lds (pre-swizzled source, lane-linear dest).
__global__ __launch_bounds__(256, 1)
void attn_fwd(const unsigned short* __restrict__ Q,
              const unsigned short* __restrict__ Kg,
              const unsigned short* __restrict__ V,
              unsigned short* __restrict__ O) {
    __shared__ __align__(16) unsigned short Kls[2][64 * 64];  // dbuf, chunk-swizzled
    __shared__ __align__(16) unsigned short Vt[64 * 64];      // [dim][key], swizzled
    __shared__ __align__(16) unsigned short Pls[4][32 * 64];

    const int tid = threadIdx.x, lane = tid & 63, wv = tid >> 6;
    const int l31 = lane & 31, b5 = lane >> 5;
    const int bid = blockIdx.x;
    const int qt = 15 - (bid >> 5);           // q-tile (128 rows), longest first
    const int bh = bid & 31;
    const size_t base = (size_t)bh * 2048 * 64;
    const unsigned short* Qp = Q + base;
    const unsigned short* Kp = Kg + base;
    const unsigned short* Vp = V + base;
    const int sr  = tid >> 3;   // staging row 0..31
    const int sc8 = tid & 7;    // staging 16B chunk
    const int ksw = (sc8 ^ (sr & 7)) * 8;     // pre-swizzled K source chunk (shorts)
    const int b = bh >> 4, h = bh & 15;

    const int q0 = qt * 128;
    const int ntblk = 2 * qt + 2;             // 64-key KV tiles staged
    const int wrow0 = q0 + wv * 32;           // wave's first q-row
    const int qrow  = wrow0 + l31;            // this lane's q-row
    const int pswz = ((l31 ^ (l31 >> 3)) & 7) << 3;

    // Q fragments (verified R8 layout): Q[d = m*16 + b5*8 + j][q = l31]
    bf16x8 qf[4];
#pragma unroll
    for (int m = 0; m < 4; m++)
        qf[m] = *(const bf16x8*)(Qp + (size_t)qrow * 64 + m * 16 + b5 * 8);

    float mst = -INFINITY, lsum = 0.f;
    f32x16 oacc0, oacc1;
#pragma unroll
    for (int r = 0; r < 16; r++) { oacc0[r] = 0.f; oacc1[r] = 0.f; }

    // prologue: K tile0 -> Kls[0] (async), V tile0 -> regs
    uint4 vreg[2];
#pragma unroll
    for (int i = 0; i < 2; i++) {
        gload16(Kp + (size_t)(sr + 32 * i) * 64 + ksw,
                &Kls[0][(sr + 32 * i) * 64 + sc8 * 8]);
        vreg[i] = *(const uint4*)(Vp + (size_t)(sr + 32 * i) * 64 + sc8 * 8);
    }

    for (int kt = 0; kt < ntblk; ++kt) {
        __syncthreads();   // prev compute done; K gload for kt drained
        // V^T scatter (verified R8 swizzle)
#pragma unroll
        for (int i = 0; i < 2; i++) {
            int r = sr + 32 * i;
            const unsigned short* pv = (const unsigned short*)&vreg[i];
#pragma unroll
            for (int j = 0; j < 8; j++) {
                int d = sc8 * 8 + j;
                Vt[d * 64 + (r ^ ((j ^ sc8) << 3))] = pv[j];
            }
        }
        __syncthreads();   // Vt ready
        if (kt + 1 < ntblk) {
#pragma unroll
            for (int i = 0; i < 2; i++) {
                gload16(Kp + (size_t)((kt + 1) * 64 + sr + 32 * i) * 64 + ksw,
                        &Kls[(kt + 1) & 1][(sr + 32 * i) * 64 + sc8 * 8]);
                vreg[i] = *(const uint4*)(Vp + (size_t)((kt + 1) * 64 + sr + 32 * i) * 64 + sc8 * 8);
            }
        }

        const unsigned short* Kb = Kls[kt & 1];
#pragma unroll
        for (int hf = 0; hf < 2; ++hf) {
            const int kb = kt * 64 + hf * 32;           // first key of this half
            if (kb > wrow0 + 31) continue;              // fully masked for wave

            // S^T = K Q^T over this 32-key half (4 k-steps of 16 dims)
            f32x16 s;
#pragma unroll
            for (int r = 0; r < 16; r++) s[r] = 0.f;
#pragma unroll
            for (int m = 0; m < 4; m++) {
                const int koff = m * 16 + b5 * 8;
                const int k0i = hf * 32 + l31;
                bf16x8 kf = *(const bf16x8*)(Kb + k0i * 64 + (koff ^ ((k0i & 7) << 3)));
                s = __builtin_amdgcn_mfma_f32_32x32x16_bf16(kf, qf[m], s, 0, 0, 0);
            }

            // causal mask if half overlaps diagonal
            if (kb + 31 > wrow0) {
#pragma unroll
                for (int r = 0; r < 16; r++) {
                    int keyg = kb + (r & 3) + 8 * (r >> 2) + 4 * b5;
                    if (keyg > qrow) s[r] = -INFINITY;
                }
            }

            // online softmax (defer-max T13)
            float xm = s[0];
#pragma unroll
            for (int r = 1; r < 16; r++) xm = fmaxf(xm, s[r]);
            float x = fmaxf(xm, __shfl_xor(xm, 32));
            if (!__all(x - mst <= 8.0f)) {
                float mnew  = fmaxf(mst, x);
                float alpha = __builtin_amdgcn_exp2f(mst - mnew);
                mst = mnew;
                lsum *= alpha;
#pragma unroll
                for (int r = 0; r < 16; r++) { oacc0[r] *= alpha; oacc1[r] *= alpha; }
            }
            float ra = 0.f;
#pragma unroll
            for (int r = 0; r < 16; r++) {
                s[r] = __builtin_amdgcn_exp2f(s[r] - mst);
                ra += s[r];
            }
            ra += __shfl_xor(ra, 32);
            lsum += ra;

            // P -> LDS (verified R8 handoff, per-half subset)
#pragma unroll
            for (int g = 0; g < 4; g++) {
                bf16x4 pk;
#pragma unroll
                for (int jj = 0; jj < 4; jj++) pk[jj] = (__bf16)s[g * 4 + jj];
                int key0 = hf * 32 + g * 8 + 4 * b5;
                *(bf16x4*)(&Pls[wv][l31 * 64 + (key0 ^ pswz)]) = pk;
            }

            // O^T += V^T P over this half (2 k-steps of 16 keys)
#pragma unroll
            for (int km2 = 0; km2 < 2; km2++) {
                const int koff = hf * 32 + km2 * 16 + b5 * 8;
                bf16x8 pf = *(const bf16x8*)(&Pls[wv][l31 * 64 + (koff ^ pswz)]);
                int d0 = l31;
                int d1 = 32 + l31;
                bf16x8 vf0 = *(const bf16x8*)(Vt + d0 * 64 + (koff ^ (((d0 ^ (d0 >> 3)) & 7) << 3)));
                bf16x8 vf1 = *(const bf16x8*)(Vt + d1 * 64 + (koff ^ (((d1 ^ (d1 >> 3)) & 7) << 3)));
                oacc0 = __builtin_amdgcn_mfma_f32_32x32x16_bf16(vf0, pf, oacc0, 0, 0, 0);
                oacc1 = __builtin_amdgcn_mfma_f32_32x32x16_bf16(vf1, pf, oacc1, 0, 0, 0);
            }
        }
    }

    // epilogue (verified R8): lane's q-row, d = dt*32 + g*8 + 4*b5 + jj
    float inv = 1.f / lsum;
    unsigned short* orow = O + ((size_t)(b * 2048 + qrow)) * 1024 + h * 64;
#pragma unroll
    for (int g = 0; g < 4; g++) {
        bf16x4 ov;
#pragma unroll
        for (int jj = 0; jj < 4; jj++) ov[jj] = (__bf16)(oacc0[g * 4 + jj] * inv);
        *(bf16x4*)(orow + g * 8 + 4 * b5) = ov;
    }
#pragma unroll
    for (int g = 0; g < 4; g++) {
        bf16x4 ov;
#pragma unroll
        for (int jj = 0; jj < 4; jj++) ov[jj] = (__bf16)(oacc1[g * 4 + jj] * inv);
        *(bf16x4*)(orow + 32 + g * 8 + 4 * b5) = ov;
    }
}

// ---------- launch ----------
extern "C" void kernel_launch(void* const* d_in, const int* in_sizes, int n_in,
                              void* d_out, int out_size, void* d_ws, size_t ws_size,
                              hipStream_t stream) {
    const float* x     = (const float*)d_in[0];
    const float* wqkv  = (const float*)d_in[1];
    const float* wproj = (const float*)d_in[2];
    float* out = (float*)d_out;

    const int BT = 4096;          // B*T
    const int DIM = 1024;
    const int NQKV = 3072;

    unsigned short* ws = (unsigned short*)d_ws;
    unsigned short* xb     = ws;
    unsigned short* wqkvb  = xb + (size_t)BT * DIM;
    unsigned short* wprojb = wqkvb + (size_t)NQKV * DIM;
    unsigned short* qb     = wprojb + (size_t)DIM * DIM;
    unsigned short* kb     = qb + (size_t)BT * DIM;
    unsigned short* vb     = kb + (size_t)BT * DIM;
    unsigned short* attb   = xb;

    cvt_all<<<(XN + WQN + WPN) / 4 / 256, 256, 0, stream>>>(x, wqkv, wproj, xb, wqkvb, wprojb);

    gemm_bt<0><<<dim3(NQKV / BN, BT / BM), 256, 0, stream>>>(xb, wqkvb, BT, NQKV, DIM,
                                                             nullptr, qb, kb, vb);
    attn_fwd<<<512, 256, 0, stream>>>(qb, kb, vb, attb);

    gemm_bt<1><<<dim3(DIM / BN, BT / BM), 256, 0, stream>>>(attb, wprojb, BT, DIM, DIM,
                                                            out, nullptr, nullptr, nullptr);
}

// Round 14
// 112.270 us; speedup vs baseline: 1.1503x; 1.1503x over previous
//
#include <hip/hip_runtime.h>
#include <hip/hip_bf16.h>
#include <stdint.h>

// ---------- types ----------
typedef __bf16 bf16x8 __attribute__((ext_vector_type(8)));
typedef __bf16 bf16x4 __attribute__((ext_vector_type(4)));
typedef float  f32x4  __attribute__((ext_vector_type(4)));

__device__ __forceinline__ unsigned short f2bf(float f) {
    unsigned u = __builtin_bit_cast(unsigned, f);
    u += 0x7fffu + ((u >> 16) & 1u);   // RNE
    return (unsigned short)(u >> 16);
}

__device__ __forceinline__ float bf2f(unsigned short u) {
    return __builtin_bit_cast(float, (unsigned)u << 16);
}

__device__ __forceinline__ void gload16(const void* g, void* l) {
    __builtin_amdgcn_global_load_lds((const __attribute__((address_space(1))) void*)g,
                                     (__attribute__((address_space(3))) void*)l, 16, 0, 0);
}

// ---------- fused fp32 -> bf16 convert for x, w_qkv, w_proj (one launch) ----------
#define XN  4194304   // 4096*1024
#define WQN 3145728   // 3072*1024
#define WPN 1048576   // 1024*1024
__global__ void cvt_all(const float* __restrict__ x, const float* __restrict__ wq,
                        const float* __restrict__ wp,
                        unsigned short* __restrict__ xb, unsigned short* __restrict__ wqb,
                        unsigned short* __restrict__ wpb) {
    int i = (blockIdx.x * blockDim.x + threadIdx.x) * 4;
    const float* src; unsigned short* dst; int off;
    if (i < XN)            { src = x;  dst = xb;  off = i; }
    else if (i < XN + WQN) { src = wq; dst = wqb; off = i - XN; }
    else                   { src = wp; dst = wpb; off = i - XN - WQN; }
    float4 v = *(const float4*)(src + off);
    ushort4 o;
    o.x = f2bf(v.x); o.y = f2bf(v.y); o.z = f2bf(v.z); o.w = f2bf(v.w);
    *(ushort4*)(dst + off) = o;
}

// ---------- GEMM C = A * B^T (proven 128x128 structure) ----------
#define BM 128
#define BN 128
#define BKK 64

template<int MODE>
__global__ void gemm_bt(const unsigned short* __restrict__ A,
                        const unsigned short* __restrict__ Bm,
                        int M, int N, int K,
                        float* __restrict__ Cf,
                        unsigned short* __restrict__ Qo,
                        unsigned short* __restrict__ Ko,
                        unsigned short* __restrict__ Vo) {
    __shared__ __align__(16) unsigned short Als[BM * BKK];
    __shared__ __align__(16) unsigned short Bls[BN * BKK];

    const int tid  = threadIdx.x;
    const int lane = tid & 63;
    const int wave = tid >> 6;
    const int wm = wave >> 1, wn = wave & 1;
    const int nwg = gridDim.x * gridDim.y;
    const int lid = blockIdx.y * gridDim.x + blockIdx.x;
    const int cpx = nwg >> 3;
    const int swz = (lid & 7) * cpx + (lid >> 3);
    const int m0 = (swz / gridDim.x) * BM, n0 = (swz % gridDim.x) * BN;
    const int l16 = lane & 15, lg = lane >> 4;

    f32x4 acc[4][4];
#pragma unroll
    for (int i = 0; i < 4; i++)
#pragma unroll
        for (int j = 0; j < 4; j++) acc[i][j] = f32x4{0.f, 0.f, 0.f, 0.f};

    const int r0 = tid >> 3;
    const int c8 = tid & 7;

    for (int k0 = 0; k0 < K; k0 += BKK) {
        __syncthreads();
#pragma unroll
        for (int i = 0; i < 4; i++) {
            gload16(A  + (size_t)(m0 + r0 + i * 32) * K + k0 + c8 * 8,
                    Als + i * 2048 + wave * 512);
            gload16(Bm + (size_t)(n0 + r0 + i * 32) * K + k0 + c8 * 8,
                    Bls + i * 2048 + wave * 512);
        }
        __syncthreads();
#pragma unroll
        for (int ks = 0; ks < 2; ++ks) {
            const int koff = ks * 32 + lg * 8;
            bf16x8 af[4], bfv[4];
#pragma unroll
            for (int mf = 0; mf < 4; ++mf)
                af[mf] = *(const bf16x8*)(Als + (wm * 64 + mf * 16 + l16) * BKK + koff);
#pragma unroll
            for (int nf = 0; nf < 4; ++nf)
                bfv[nf] = *(const bf16x8*)(Bls + (wn * 64 + nf * 16 + l16) * BKK + koff);
#pragma unroll
            for (int mf = 0; mf < 4; ++mf)
#pragma unroll
                for (int nf = 0; nf < 4; ++nf)
                    acc[mf][nf] = __builtin_amdgcn_mfma_f32_16x16x32_bf16(af[mf], bfv[nf], acc[mf][nf], 0, 0, 0);
        }
    }

#pragma unroll
    for (int mf = 0; mf < 4; ++mf) {
        int gm = m0 + wm * 64 + mf * 16 + (lg << 2);
#pragma unroll
        for (int nf = 0; nf < 4; ++nf) {
            int gn = n0 + wn * 64 + nf * 16 + l16;
            if (MODE == 0) {
                int which = gn >> 10;
                int rem = gn & 1023;
                int h = rem >> 6, d = rem & 63;
                unsigned short* dst = (which == 0) ? Qo : (which == 1) ? Ko : Vo;
                float s = (which == 0) ? 0.180336884f : 1.0f;   // 0.125 * log2(e) for Q
#pragma unroll
                for (int j = 0; j < 4; j++) {
                    int m = gm + j;
                    int b = m >> 11, t = m & 2047;
                    dst[((size_t)((b << 4) + h) * 2048 + t) * 64 + d] = f2bf(acc[mf][nf][j] * s);
                }
            } else {
#pragma unroll
                for (int j = 0; j < 4; j++)
                    Cf[(size_t)(gm + j) * N + gn] = acc[mf][nf][j];
            }
        }
    }
}

// ---------- causal flash attention with K-SPLIT (R7 pipeline, 2x TLP) ----------
// 1024 blocks: qt = 15-(bid>>6), half = (bid>>5)&1, bh = bid&31. Halves of the causal
// KV range ([0,qt+1) and [qt+1,2qt+2) tiles) are EQUAL work. 4 blocks/CU, 32 waves/CU.
// Each half-block stores unnormalized O~ (bf16) + per-row (m,l); combine merges.
__global__ __launch_bounds__(512, 4)
void attn_split(const unsigned short* __restrict__ Q,
                const unsigned short* __restrict__ Kg,
                const unsigned short* __restrict__ V,
                unsigned short* __restrict__ O1,
                unsigned short* __restrict__ O2,
                float2* __restrict__ st1,
                float2* __restrict__ st2) {
    __shared__ __align__(16) unsigned short Kls[64 * 64];
    __shared__ __align__(16) unsigned short Vt[64 * 64];   // [dim][key], swizzled
    __shared__ __align__(16) unsigned short Pls[8][16 * 64];

    const int tid = threadIdx.x, lane = tid & 63, wv = tid >> 6;
    const int l16 = lane & 15, lg = lane >> 4;
    const int bid = blockIdx.x;
    const int qt   = 15 - (bid >> 6);         // q-tile (128 rows), longest first
    const int half = (bid >> 5) & 1;
    const int bh   = bid & 31;
    const size_t base = (size_t)bh * 2048 * 64;
    const unsigned short* Qp = Q + base;
    const unsigned short* Kp = Kg + base;
    const unsigned short* Vp = V + base;
    const int sr  = tid >> 3;
    const int sc8 = tid & 7;
    const int b = bh >> 4, h = bh & 15;

    const int q0 = qt * 128;
    const int lo = half ? (qt + 1) : 0;       // tile range [lo, hi)
    const int hi = half ? (2 * qt + 2) : (qt + 1);
    const int qrow = q0 + wv * 16 + l16;
    const int qtw  = (q0 + wv * 16) >> 6;     // wave's diagonal KV-tile index

    bf16x8 qf[2];
#pragma unroll
    for (int ks = 0; ks < 2; ks++)
        qf[ks] = *(const bf16x8*)(Qp + (size_t)qrow * 64 + ks * 32 + lg * 8);

    float mst = -INFINITY, lsum = 0.f;
    f32x4 oacc[4];
#pragma unroll
    for (int nf = 0; nf < 4; nf++) oacc[nf] = f32x4{0.f, 0.f, 0.f, 0.f};

    uint4 kreg, vreg;
    kreg = *(const uint4*)(Kp + (size_t)(lo * 64 + sr) * 64 + sc8 * 8);
    vreg = *(const uint4*)(Vp + (size_t)(lo * 64 + sr) * 64 + sc8 * 8);

    for (int kt = lo; kt < hi; ++kt) {
        __syncthreads();
        {
            int r = sr;
            *(uint4*)(Kls + r * 64 + ((sc8 ^ (r & 7)) << 3)) = kreg;
            const unsigned short* pv = (const unsigned short*)&vreg;
#pragma unroll
            for (int j = 0; j < 8; j++) {
                int d = sc8 * 8 + j;
                Vt[d * 64 + (r ^ ((j ^ sc8) << 3))] = pv[j];
            }
        }
        __syncthreads();
        if (kt + 1 < hi) {
            kreg = *(const uint4*)(Kp + (size_t)((kt + 1) * 64 + sr) * 64 + sc8 * 8);
            vreg = *(const uint4*)(Vp + (size_t)((kt + 1) * 64 + sr) * 64 + sc8 * 8);
        }

        if (kt > qtw) continue;   // fully masked for this wave

        f32x4 sacc[4];
#pragma unroll
        for (int nf = 0; nf < 4; nf++) sacc[nf] = f32x4{0.f, 0.f, 0.f, 0.f};
#pragma unroll
        for (int ks = 0; ks < 2; ks++) {
            const int koff = ks * 32 + lg * 8;
            bf16x8 kf[4];
#pragma unroll
            for (int nf = 0; nf < 4; nf++) {
                int key = nf * 16 + l16;
                kf[nf] = *(const bf16x8*)(Kls + key * 64 + (koff ^ ((key & 7) << 3)));
            }
#pragma unroll
            for (int nf = 0; nf < 4; nf++)
                sacc[nf] = __builtin_amdgcn_mfma_f32_16x16x32_bf16(kf[nf], qf[ks], sacc[nf], 0, 0, 0);
        }

        if (kt == qtw) {
#pragma unroll
            for (int nf = 0; nf < 4; nf++) {
                int keyb = kt * 64 + nf * 16 + (lg << 2);
#pragma unroll
                for (int j = 0; j < 4; j++)
                    if (keyb + j > qrow) sacc[nf][j] = -INFINITY;
            }
        }

        float xm[4];
#pragma unroll
        for (int nf = 0; nf < 4; nf++)
            xm[nf] = fmaxf(fmaxf(sacc[nf][0], sacc[nf][1]), fmaxf(sacc[nf][2], sacc[nf][3]));
        float x = fmaxf(fmaxf(xm[0], xm[1]), fmaxf(xm[2], xm[3]));
        x = fmaxf(x, __shfl_xor(x, 16));
        x = fmaxf(x, __shfl_xor(x, 32));
        if (!__all(x - mst <= 8.0f)) {   // T13 defer-max
            float mnew  = fmaxf(mst, x);
            float alpha = __builtin_amdgcn_exp2f(mst - mnew);
            mst = mnew;
            lsum *= alpha;
#pragma unroll
            for (int nf = 0; nf < 4; nf++)
#pragma unroll
                for (int j = 0; j < 4; j++) oacc[nf][j] *= alpha;
        }
        float ps[4];
#pragma unroll
        for (int nf = 0; nf < 4; nf++) {
#pragma unroll
            for (int j = 0; j < 4; j++)
                sacc[nf][j] = __builtin_amdgcn_exp2f(sacc[nf][j] - mst);
            ps[nf] = (sacc[nf][0] + sacc[nf][1]) + (sacc[nf][2] + sacc[nf][3]);
        }
        float rs = (ps[0] + ps[1]) + (ps[2] + ps[3]);
        rs += __shfl_xor(rs, 16);
        rs += __shfl_xor(rs, 32);
        lsum += rs;

#pragma unroll
        for (int nf = 0; nf < 4; nf++) {
            bf16x4 pk;
#pragma unroll
            for (int j = 0; j < 4; j++) pk[j] = (__bf16)sacc[nf][j];
            int keyb = nf * 16 + (lg << 2);
            *(bf16x4*)(&Pls[wv][l16 * 64 + (keyb ^ ((l16 & 7) << 3))]) = pk;
        }

#pragma unroll
        for (int ks = 0; ks < 2; ks++) {
            const int koff = ks * 32 + lg * 8;
            bf16x8 pf = *(const bf16x8*)(&Pls[wv][l16 * 64 + (koff ^ ((l16 & 7) << 3))]);
            bf16x8 vf[4];
#pragma unroll
            for (int nf = 0; nf < 4; nf++) {
                int d = nf * 16 + l16;
                vf[nf] = *(const bf16x8*)(Vt + d * 64 + (koff ^ (((d & 7) ^ ((d >> 3) & 7)) << 3)));
            }
#pragma unroll
            for (int nf = 0; nf < 4; nf++)
                oacc[nf] = __builtin_amdgcn_mfma_f32_16x16x32_bf16(vf[nf], pf, oacc[nf], 0, 0, 0);
        }
    }

    // epilogue: UNNORMALIZED O~ + stats (combine divides)
    {
        unsigned short* Op = half ? O2 : O1;
        unsigned short* orow = Op + ((size_t)(b * 2048 + qrow)) * 1024 + h * 64;
#pragma unroll
        for (int nf = 0; nf < 4; nf++) {
            bf16x4 ov;
#pragma unroll
            for (int j = 0; j < 4; j++) ov[j] = (__bf16)oacc[nf][j];
            *(bf16x4*)(orow + nf * 16 + (lg << 2)) = ov;
        }
        if (lg == 0) {
            float2* st = half ? st2 : st1;
            st[bh * 2048 + qrow] = make_float2(mst, lsum);
        }
    }
}

// ---------- combine: O = (a1*O1~ + a2*O2~) / (a1*l1 + a2*l2), in-place into O1 ----------
__global__ void combine(unsigned short* __restrict__ O1,
                        const unsigned short* __restrict__ O2,
                        const float2* __restrict__ st1,
                        const float2* __restrict__ st2) {
    int idx = blockIdx.x * 256 + threadIdx.x;    // 524288 chunks of 8 bf16
    int f = idx * 8;
    int h = (f & 1023) >> 6;
    int t = (f >> 10) & 2047;
    int b = f >> 21;
    int srow = ((b << 4) + h) * 2048 + t;
    float2 s1 = st1[srow], s2 = st2[srow];
    float m = fmaxf(s1.x, s2.x);
    float a1 = __builtin_amdgcn_exp2f(s1.x - m);
    float a2 = __builtin_amdgcn_exp2f(s2.x - m);
    float inv = 1.f / (a1 * s1.y + a2 * s2.y);
    a1 *= inv; a2 *= inv;
    uint4 u1 = *(const uint4*)(O1 + f);
    uint4 u2 = *(const uint4*)(O2 + f);
    const unsigned short* p1 = (const unsigned short*)&u1;
    const unsigned short* p2 = (const unsigned short*)&u2;
    bf16x8 outv;
#pragma unroll
    for (int j = 0; j < 8; j++)
        outv[j] = (__bf16)(a1 * bf2f(p1[j]) + a2 * bf2f(p2[j]));
    *(bf16x8*)(O1 + f) = outv;
}

// ---------- launch ----------
extern "C" void kernel_launch(void* const* d_in, const int* in_sizes, int n_in,
                              void* d_out, int out_size, void* d_ws, size_t ws_size,
                              hipStream_t stream) {
    const float* x     = (const float*)d_in[0];
    const float* wqkv  = (const float*)d_in[1];
    const float* wproj = (const float*)d_in[2];
    float* out = (float*)d_out;

    const int BT = 4096;          // B*T
    const int DIM = 1024;
    const int NQKV = 3072;

    unsigned short* ws = (unsigned short*)d_ws;
    unsigned short* xb     = ws;
    unsigned short* wqkvb  = xb + (size_t)BT * DIM;
    unsigned short* wprojb = wqkvb + (size_t)NQKV * DIM;
    unsigned short* qb     = wprojb + (size_t)DIM * DIM;
    unsigned short* kb     = qb + (size_t)BT * DIM;
    unsigned short* vb     = kb + (size_t)BT * DIM;
    unsigned short* attb   = xb;                          // O1 partial, then final O

    // d_out (16MB fp32) as pre-gemm2 scratch: O2 partial (8MB) + stats (1MB)
    unsigned short* o2  = (unsigned short*)d_out;
    float2* st1 = (float2*)((char*)d_out + 8u * 1024 * 1024);
    float2* st2 = st1 + 65536;

    cvt_all<<<(XN + WQN + WPN) / 4 / 256, 256, 0, stream>>>(x, wqkv, wproj, xb, wqkvb, wprojb);

    gemm_bt<0><<<dim3(NQKV / BN, BT / BM), 256, 0, stream>>>(xb, wqkvb, BT, NQKV, DIM,
                                                             nullptr, qb, kb, vb);

    attn_split<<<1024, 512, 0, stream>>>(qb, kb, vb, attb, o2, st1, st2);
    combine<<<2048, 256, 0, stream>>>(attb, o2, st1, st2);

    gemm_bt<1><<<dim3(DIM / BN, BT / BM), 256, 0, stream>>>(attb, wprojb, BT, DIM, DIM,
                                                            out, nullptr, nullptr, nullptr);
}